// Round 7
// baseline (2619.596 us; speedup 1.0000x reference)
//
#include <hip/hip_runtime.h>
#include <cstdint>
#include <cstddef>

// Problem constants: N=4096, S=31, C=512, H=8, D=64
#define N_ 4096
#define S_ 31
#define C_ 512
#define H_ 8
#define M_ (N_*S_)     // 126976
#define NH_ (N_*H_)    // 32768

typedef unsigned short u16;
typedef unsigned char  u8;
typedef __bf16 v8bf __attribute__((ext_vector_type(8)));
typedef float  v4f  __attribute__((ext_vector_type(4)));
typedef float  v2f  __attribute__((ext_vector_type(2)));
typedef unsigned short v8u __attribute__((ext_vector_type(8)));
typedef unsigned short v4u __attribute__((ext_vector_type(4)));

// Workspace layout (bytes):
//   0        : wbf  bf16, 4 matrices, each in MFMA-fragment order:
//              [j16 (0..31)][kk (0..15)][lane (0..63)][e (0..7)]
//   2 MB     : statsf, 6144 f32:
//     [0:512] xsum [512:1024] xsumsq [1024:1536] (unused) [1536:2048] (unused)
//     [2048:3072] esum(padded1024) [3072:4096] esumsq [4096:5120] s2p [5120:6144] sh2p
//   WS_Q : energy bf16 [nh][32][32] (67 MB)
//   WS_K : (unused)
//   WS_V : Vt fp8 [n][h][64][32]  (67 MB)
#define WS_STATS 2097152
#define WS_Q (WS_STATS + 32768)
#define WS_K (WS_Q + 67108864)
#define WS_V (WS_K + 67108864)

#define SCALE_QK 16.0f
#define SCALE_V  16.0f

__device__ __forceinline__ u16 f2bf(float f) {
  union { float f; unsigned u; } v; v.f = f;
  unsigned r = v.u + 0x7FFFu + ((v.u >> 16) & 1u);
  return (u16)(r >> 16);
}
__device__ __forceinline__ float bf2f(u16 v) {
  union { unsigned u; float f; } w; w.u = ((unsigned)v) << 16; return w.f;
}
__device__ __forceinline__ unsigned enc4(float a, float b, float c, float d) {
  int w = __builtin_amdgcn_cvt_pk_fp8_f32(a, b, 0, false);
  w = __builtin_amdgcn_cvt_pk_fp8_f32(c, d, w, true);
  return (unsigned)w;
}
__device__ __forceinline__ v8bf dec8(uint2 u) {
  v2f p0 = __builtin_amdgcn_cvt_pk_f32_fp8((int)u.x, false);
  v2f p1 = __builtin_amdgcn_cvt_pk_f32_fp8((int)u.x, true);
  v2f p2 = __builtin_amdgcn_cvt_pk_f32_fp8((int)u.y, false);
  v2f p3 = __builtin_amdgcn_cvt_pk_f32_fp8((int)u.y, true);
  v8bf r;
  r[0]=(__bf16)p0[0]; r[1]=(__bf16)p0[1]; r[2]=(__bf16)p1[0]; r[3]=(__bf16)p1[1];
  r[4]=(__bf16)p2[0]; r[5]=(__bf16)p2[1]; r[6]=(__bf16)p3[0]; r[7]=(__bf16)p3[1];
  return r;
}

// ---------------- K0: weights fp32 -> bf16 in MFMA fragment order; zero stat accumulators
__global__ void k_init(const float* wq, const float* wk, const float* wv, const float* wo,
                       u16* wbf, float* statsf) {
  int gid = blockIdx.x * 256 + threadIdx.x;   // 4096*256 = 1048576 = 4*262144
  if (gid < 6144) statsf[gid] = 0.0f;
  int m = gid >> 18, o = gid & 262143;
  int e    = o & 7;
  int lane = (o >> 3) & 63;
  int kk   = (o >> 9) & 15;
  int j16  = o >> 13;
  int j = j16 * 16 + (lane & 15);
  int k = kk * 32 + (lane >> 4) * 8 + e;
  const float* src = (m == 0) ? wq : (m == 1) ? wk : (m == 2) ? wv : wo;
  wbf[(size_t)m * 262144 + o] = f2bf(src[j * 512 + k]);
}

// ---------------- K1: per-channel sum/sumsq of x (float4 loads)
__global__ void __launch_bounds__(512, 8) k_xstats(const float* __restrict__ x, float* statsf) {
  __shared__ float4 rs[512], rq[512];
  int t = threadIdx.x;
  int c4 = (t & 127) * 4;
  int r0 = blockIdx.x * 128 + (t >> 7) * 32;
  float4 s = {0,0,0,0}, sq = {0,0,0,0};
  const float* p = x + (size_t)r0 * C_ + c4;
  for (int i = 0; i < 32; ++i) {
    float4 v = *(const float4*)(p + (size_t)i * C_);
    s.x += v.x; s.y += v.y; s.z += v.z; s.w += v.w;
    sq.x += v.x*v.x; sq.y += v.y*v.y; sq.z += v.z*v.z; sq.w += v.w*v.w;
  }
  rs[t] = s; rq[t] = sq;
  __syncthreads();
  if (t < 128) {
    #pragma unroll
    for (int g = 1; g < 4; ++g) {
      float4 a = rs[t + g*128], b = rq[t + g*128];
      s.x += a.x; s.y += a.y; s.z += a.z; s.w += a.w;
      sq.x += b.x; sq.y += b.y; sq.z += b.z; sq.w += b.w;
    }
    atomicAdd(&statsf[c4+0], s.x); atomicAdd(&statsf[c4+1], s.y);
    atomicAdd(&statsf[c4+2], s.z); atomicAdd(&statsf[c4+3], s.w);
    atomicAdd(&statsf[512+c4+0], sq.x); atomicAdd(&statsf[512+c4+1], sq.y);
    atomicAdd(&statsf[512+c4+2], sq.z); atomicAdd(&statsf[512+c4+3], sq.w);
  }
}

// 64x32-per-pass GEMM over staged A fragments and fragment-order B.
// Depth-2 B prefetch ring (b[3][2]) hides L2 latency; acc is 32 regs so the
// ring fits under the 128-VGPR/4-wave budget. SWZ selects the A swizzle.
template<int SWZ>
__device__ __forceinline__ void gemm64x32(const u16* sa, const u16* B0, v4f (&acc)[4][2], int lane) {
  #pragma unroll
  for (int m = 0; m < 4; ++m)
    #pragma unroll
    for (int c = 0; c < 2; ++c) acc[m][c] = (v4f){0,0,0,0};
  v8bf b[3][2];
  #pragma unroll
  for (int p = 0; p < 2; ++p)
    #pragma unroll
    for (int c = 0; c < 2; ++c)
      b[p][c] = *(const v8bf*)(B0 + (size_t)c * 8192 + p * 512);
  #pragma unroll
  for (int kk = 0; kk < 16; ++kk) {
    if (kk + 2 < 16) {
      #pragma unroll
      for (int c = 0; c < 2; ++c)
        b[(kk+2)%3][c] = *(const v8bf*)(B0 + (size_t)c * 8192 + (kk+2) * 512);
    }
    v8bf a[4];
    #pragma unroll
    for (int m = 0; m < 4; ++m)
      a[m] = *(const v8bf*)(sa + ((((kk*4 + m) << 6) | (SWZ ? (lane ^ (kk & 7)) : lane)) << 3));
    #pragma unroll
    for (int m = 0; m < 4; ++m)
      #pragma unroll
      for (int c = 0; c < 2; ++c)
        acc[m][c] = __builtin_amdgcn_mfma_f32_16x16x32_bf16(a[m], b[kk%3][c], acc[m][c], 0, 0, 0);
  }
}

// ---------------- K2: normalize -> QKV GEMMs -> in-kernel energy = Q K^T
// Block = 2 batch items (64 padded rows), 512 thr, LDS 68 KB -> 2 blocks/CU.
__global__ void __launch_bounds__(512, 4)
k_qkv(const float* __restrict__ x, const u16* __restrict__ wbf,
      const float* __restrict__ statsf, const float* __restrict__ gamma,
      const float* __restrict__ beta, u8* __restrict__ eg8, u8* __restrict__ vt) {
  __shared__ float s_scale[C_], s_shift[C_];
  __shared__ u16 s_a[16*4*64*8];   // 64 KB; fragment order; reused as QK scratch later
  int t = threadIdx.x, nblk = blockIdx.x;
  int wave = t >> 6, lane = t & 63, l15 = lane & 15, quad = lane >> 4;
  {
    float su = statsf[t], sqv = statsf[512 + t];
    float mu  = su * (1.0f / (float)M_);
    float var = sqv * (1.0f / (float)M_) - mu * mu;
    float sc  = rsqrtf(var + 1e-5f) * gamma[t];
    s_scale[t] = sc;
    s_shift[t] = beta[t] - mu * sc;
  }
  __syncthreads();

  // stage normalized A in fragment order (row 31 of each n zeroed): 64 rows
  const float* xb = x + (size_t)nblk * 2 * S_ * C_;
  for (int it = 0; it < 8; ++it) {
    int idx = t + it * 512;
    int row = idx >> 6, c8 = (idx & 63) << 3;
    int nl = row >> 5, s = row & 31;
    int kk = c8 >> 5, q4 = (c8 >> 3) & 3, mt = row >> 4, r15 = row & 15;
    u16* dst = s_a + ((((kk*4 + mt) << 6) | ((q4*16 + r15) ^ (kk & 7))) << 3);
    v8u o;
    if (s == 31) { o = (v8u){0,0,0,0,0,0,0,0}; }
    else {
      const float* g = xb + (size_t)(nl * 31 + s) * C_ + c8;
      float4 a = *(const float4*)g, b = *(const float4*)(g + 4);
      o[0]=f2bf(a.x*s_scale[c8+0]+s_shift[c8+0]); o[1]=f2bf(a.y*s_scale[c8+1]+s_shift[c8+1]);
      o[2]=f2bf(a.z*s_scale[c8+2]+s_shift[c8+2]); o[3]=f2bf(a.w*s_scale[c8+3]+s_shift[c8+3]);
      o[4]=f2bf(b.x*s_scale[c8+4]+s_shift[c8+4]); o[5]=f2bf(b.y*s_scale[c8+5]+s_shift[c8+5]);
      o[6]=f2bf(b.z*s_scale[c8+6]+s_shift[c8+6]); o[7]=f2bf(b.w*s_scale[c8+7]+s_shift[c8+7]);
    }
    *(v8u*)dst = o;
  }
  __syncthreads();

  // ---- V GEMM (matrix 2) -> vt fp8 [n][h=wave][64d][32s]; two 64x32 passes
  #pragma unroll
  for (int cs = 0; cs < 2; ++cs) {
    v4f acc[4][2];
    gemm64x32<1>(s_a, wbf + (size_t)2 * 262144 + (size_t)wave * 32768 + cs * 16384 + (size_t)lane * 8, acc, lane);
    #pragma unroll
    for (int m = 0; m < 4; ++m) {
      int rbase = m*16 + quad*4;
      int nl = rbase >> 5, s0 = rbase & 31;
      size_t nbase = (size_t)(nblk*2 + nl) * 8;
      #pragma unroll
      for (int c = 0; c < 2; ++c) {
        int d = cs*32 + c*16 + l15;
        unsigned w = enc4(acc[m][c][0]*SCALE_V, acc[m][c][1]*SCALE_V,
                          acc[m][c][2]*SCALE_V, acc[m][c][3]*SCALE_V);
        *(unsigned*)(vt + ((nbase + wave) * 2048) + d*32 + s0) = w;
      }
    }
  }

  // ---- Q GEMM (matrix 0) -> fp8 packed in regs (head = wave, both n)
  unsigned qpack[16];
  #pragma unroll
  for (int cs = 0; cs < 2; ++cs) {
    v4f acc[4][2];
    gemm64x32<1>(s_a, wbf + (size_t)0 * 262144 + (size_t)wave * 32768 + cs * 16384 + (size_t)lane * 8, acc, lane);
    #pragma unroll
    for (int m = 0; m < 4; ++m)
      #pragma unroll
      for (int c = 0; c < 2; ++c)
        qpack[m*4 + cs*2 + c] = enc4(acc[m][c][0]*SCALE_QK, acc[m][c][1]*SCALE_QK,
                                     acc[m][c][2]*SCALE_QK, acc[m][c][3]*SCALE_QK);
  }

  // ---- K GEMM (matrix 1) -> fp8 packed in regs
  unsigned kpack[16];
  #pragma unroll
  for (int cs = 0; cs < 2; ++cs) {
    v4f acc[4][2];
    gemm64x32<1>(s_a, wbf + (size_t)1 * 262144 + (size_t)wave * 32768 + cs * 16384 + (size_t)lane * 8, acc, lane);
    #pragma unroll
    for (int m = 0; m < 4; ++m)
      #pragma unroll
      for (int c = 0; c < 2; ++c)
        kpack[m*4 + cs*2 + c] = enc4(acc[m][c][0]*SCALE_QK, acc[m][c][1]*SCALE_QK,
                                     acc[m][c][2]*SCALE_QK, acc[m][c][3]*SCALE_QK);
  }

  __syncthreads();   // all waves done reading s_a fragments -> safe to reuse as scratch

  // per-wave scratch: Q tile [r(64)][d(64)] fp8 at +0, K tile at +4096.
  u8* scr = (u8*)s_a + wave * 8192;
  #pragma unroll
  for (int m = 0; m < 4; ++m)
    #pragma unroll
    for (int c = 0; c < 4; ++c) {
      int d = c*16 + l15;
      #pragma unroll
      for (int reg = 0; reg < 4; ++reg) {
        int r = m*16 + quad*4 + reg;
        int dd = d ^ ((r & 7) << 3);
        scr[r*64 + dd]        = (u8)(qpack[m*4+c] >> (reg*8));
        scr[4096 + r*64 + dd] = (u8)(kpack[m*4+c] >> (reg*8));
      }
    }

  // ---- energy = Q K^T per (n, h=wave), bf16 [32][32] -> eg
  const float inv = 1.0f / (SCALE_QK * SCALE_QK);
  #pragma unroll 1
  for (int n = 0; n < 2; ++n) {
    v8bf A[2][2], B[2][2];
    #pragma unroll
    for (int mt = 0; mt < 2; ++mt)
      #pragma unroll
      for (int kk = 0; kk < 2; ++kk) {
        int r = n*32 + mt*16 + l15;
        int dA = (kk*32 + quad*8) ^ ((r & 7) << 3);
        A[mt][kk] = dec8(*(const uint2*)(scr + r*64 + dA));
        B[mt][kk] = dec8(*(const uint2*)(scr + 4096 + r*64 + dA));
      }
    u16* ep = (u16*)(eg8 + (((size_t)(nblk*2 + n) * 8 + wave) * 2048));
    #pragma unroll
    for (int qt = 0; qt < 2; ++qt)
      #pragma unroll
      for (int kt = 0; kt < 2; ++kt) {
        v4f a2 = {0,0,0,0};
        a2 = __builtin_amdgcn_mfma_f32_16x16x32_bf16(A[qt][0], B[kt][0], a2, 0, 0, 0);
        a2 = __builtin_amdgcn_mfma_f32_16x16x32_bf16(A[qt][1], B[kt][1], a2, 0, 0, 0);
        int k = kt*16 + l15;
        #pragma unroll
        for (int reg = 0; reg < 4; ++reg) {
          int q = qt*16 + quad*4 + reg;
          ep[q*32 + k] = f2bf(a2[reg] * inv);
        }
      }
  }
}

// ---------------- K4: energy per-padded-channel sum/sumsq over (n,h)
__global__ void __launch_bounds__(256, 8) k_estats(const u16* __restrict__ eg, float* statsf) {
  int t = threadIdx.x;
  int r0 = blockIdx.x * 32;
  float s[4] = {0,0,0,0}, sq[4] = {0,0,0,0};
  for (int i = 0; i < 32; ++i) {
    uint2 u = *(const uint2*)(eg + (size_t)(r0 + i) * 1024 + t * 4);
    float v0 = bf2f((u16)(u.x & 0xffff)), v1 = bf2f((u16)(u.x >> 16));
    float v2 = bf2f((u16)(u.y & 0xffff)), v3 = bf2f((u16)(u.y >> 16));
    s[0]+=v0; s[1]+=v1; s[2]+=v2; s[3]+=v3;
    sq[0]+=v0*v0; sq[1]+=v1*v1; sq[2]+=v2*v2; sq[3]+=v3*v3;
  }
  #pragma unroll
  for (int j = 0; j < 4; ++j) {
    atomicAdd(&statsf[2048 + t*4 + j], s[j]);
    atomicAdd(&statsf[3072 + t*4 + j], sq[j]);
  }
}

__global__ void k_finalize_e(const float* pg, const float* pb, float* statsf) {
  int c = threadIdx.x;       // 1024
  int q = c >> 5, k = c & 31;
  const float invC = 0.04419417382415922f;   // 1/sqrt(512)
  float s2 = 0.f, sh2 = 0.f;
  if (q < 31 && k < 31) {
    int ss = q*31 + k;
    float mu  = statsf[2048 + c] * (1.0f / (float)NH_);
    float var = statsf[3072 + c] * (1.0f / (float)NH_) - mu * mu;
    float sc  = rsqrtf(var + 1e-5f) * pg[ss];
    s2  = sc * invC;
    sh2 = (pb[ss] - mu * sc) * invC;
  }
  statsf[4096 + c] = s2;
  statsf[5120 + c] = sh2;
}

// ---------------- K5: softmax + A*V -> LDS A, then O-proj GEMM + bias + residual
__global__ void __launch_bounds__(512, 4)
k_oproj(const float* __restrict__ x, const u16* __restrict__ wbf,
        const float* __restrict__ statsf, const u16* __restrict__ eg,
        const u8* __restrict__ vt, const float* __restrict__ bo, float* __restrict__ out) {
  __shared__ u16 s_a[16*4*64*8];        // 64 KB, fragment order
  __shared__ u16 s_attn[8][1024];       // per-wave [32 q][32 k] bf16, 16 KB
  int t = threadIdx.x, nblk = blockIdx.x;
  int wave = t >> 6, lane = t & 63, l15 = lane & 15, quad = lane >> 4;

  // phase 1: 16 tasks = 2n x 8h; wave handles 2
  int q = lane & 31, half = lane >> 5;
  #pragma unroll 1
  for (int tk = 0; tk < 2; ++tk) {
    int task = wave * 2 + tk;
    int nl = task >> 3, h = task & 7;
    size_t nh = (size_t)(nblk*2 + nl) * 8 + h;
    const u16* ep = eg + nh * 1024;
    int cb = q*32 + half*16;
    v8u e0 = *(const v8u*)(ep + cb);
    v8u e1 = *(const v8u*)(ep + cb + 8);
    const float* s2g  = statsf + 4096 + cb;
    const float* sh2g = statsf + 5120 + cb;
    float lg[16];
    #pragma unroll
    for (int j = 0; j < 8; ++j) lg[j]   = bf2f(e0[j]) * s2g[j]   + sh2g[j];
    #pragma unroll
    for (int j = 0; j < 8; ++j) lg[8+j] = bf2f(e1[j]) * s2g[8+j] + sh2g[8+j];
    if (half) lg[15] = -1e30f;            // k=31 pad excluded
    float mx = lg[0];
    #pragma unroll
    for (int j = 1; j < 16; ++j) mx = fmaxf(mx, lg[j]);
    mx = fmaxf(mx, __shfl_xor(mx, 32));
    float sum = 0.f;
    #pragma unroll
    for (int j = 0; j < 16; ++j) { lg[j] = __expf(lg[j] - mx); sum += lg[j]; }
    sum += __shfl_xor(sum, 32);
    float r = (q == 31) ? 0.f : (1.0f / sum);
    v8u o0, o1;
    #pragma unroll
    for (int j = 0; j < 8; ++j) { o0[j] = f2bf(lg[j] * r); o1[j] = f2bf(lg[8+j] * r); }
    *(v8u*)(&s_attn[wave][cb]) = o0;
    *(v8u*)(&s_attn[wave][cb + 8]) = o1;
    // A*V (transposed) for this (n,h)
    v8bf a0 = *(const v8bf*)(&s_attn[wave][(l15)*32 + quad*8]);       // attn rows 0..15
    v8bf a1 = *(const v8bf*)(&s_attn[wave][(16 + l15)*32 + quad*8]);  // attn rows 16..31
    const float invV = 1.0f / SCALE_V;
    #pragma unroll
    for (int ct = 0; ct < 4; ++ct) {
      uint2 u = *(const uint2*)(vt + nh*2048 + (ct*16 + l15)*32 + quad*8);
      v8bf b = dec8(u);
      v4f c0 = {0,0,0,0}, c1 = {0,0,0,0};
      c0 = __builtin_amdgcn_mfma_f32_16x16x32_bf16(b, a0, c0, 0, 0, 0);
      c1 = __builtin_amdgcn_mfma_f32_16x16x32_bf16(b, a1, c1, 0, 0, 0);
      int kkA = h*2 + (ct>>1);
      int qA  = (ct*2 + (quad>>1)) & 3;
      int pA  = (quad&1)*4;
      v4u w0, w1;
      #pragma unroll
      for (int reg = 0; reg < 4; ++reg) {
        w0[reg] = f2bf(c0[reg] * invV);
        w1[reg] = f2bf(c1[reg] * invV);
      }
      *(v4u*)(&s_a[((((kkA*4 + nl*2 + 0) << 6) | (qA*16 + l15)) << 3) + pA]) = w0;
      *(v4u*)(&s_a[((((kkA*4 + nl*2 + 1) << 6) | (qA*16 + l15)) << 3) + pA]) = w1;
    }
  }
  __syncthreads();

  // phase 2: O-proj GEMM (matrix 3 of wbf, fragment order), bias + residual.
  // Two 64x32 passes with B prefetch ring (no A swizzle in this LDS layout).
  #pragma unroll
  for (int cs = 0; cs < 2; ++cs) {
    v4f acc[4][2];
    gemm64x32<0>(s_a, wbf + (size_t)3 * 262144 + (size_t)wave * 32768 + cs * 16384 + (size_t)lane * 8, acc, lane);
    #pragma unroll
    for (int m = 0; m < 4; ++m) {
      int rbase = m*16 + quad*4;
      int nl = rbase >> 5, s0 = rbase & 31;
      #pragma unroll
      for (int c = 0; c < 2; ++c) {
        int j = wave*64 + cs*32 + c*16 + l15;
        float bj = bo[j];
        #pragma unroll
        for (int reg = 0; reg < 4; ++reg) {
          int s = s0 + reg;
          if (s < 31) {
            size_t off = (size_t)((nblk*2 + nl) * 31 + s) * C_ + j;
            out[off] = acc[m][c][reg] + bj + x[off];
          }
        }
      }
    }
  }
}

extern "C" void kernel_launch(void* const* d_in, const int* in_sizes, int n_in,
                              void* d_out, int out_size, void* d_ws, size_t ws_size,
                              hipStream_t stream) {
  const float* x     = (const float*)d_in[0];
  const float* gamma = (const float*)d_in[1];
  const float* beta  = (const float*)d_in[2];
  const float* wq    = (const float*)d_in[3];
  const float* wk    = (const float*)d_in[4];
  const float* wv    = (const float*)d_in[5];
  const float* wo    = (const float*)d_in[6];
  const float* bo    = (const float*)d_in[7];
  const float* pg    = (const float*)d_in[8];
  const float* pb    = (const float*)d_in[9];

  char* ws = (char*)d_ws;
  u16*   wbf    = (u16*)ws;
  float* statsf = (float*)(ws + WS_STATS);
  u8*    eg8    = (u8*)(ws + WS_Q);
  u8*    vtp    = (u8*)(ws + WS_V);
  float* outp   = (float*)d_out;

  k_init<<<4096, 256, 0, stream>>>(wq, wk, wv, wo, wbf, statsf);
  k_xstats<<<992, 512, 0, stream>>>(x, statsf);
  k_qkv<<<2048, 512, 0, stream>>>(x, wbf, statsf, gamma, beta, eg8, vtp);
  k_estats<<<1024, 256, 0, stream>>>((const u16*)eg8, statsf);
  k_finalize_e<<<1, 1024, 0, stream>>>(pg, pb, statsf);
  k_oproj<<<2048, 512, 0, stream>>>(x, wbf, statsf, (const u16*)eg8, vtp, bo, outp);
}

// Round 8
// 985.680 us; speedup vs baseline: 2.6577x; 2.6577x over previous
//
#include <hip/hip_runtime.h>
#include <cstdint>
#include <cstddef>

// Problem constants: N=4096, S=31, C=512, H=8, D=64
#define N_ 4096
#define S_ 31
#define C_ 512
#define H_ 8
#define M_ (N_*S_)     // 126976
#define NH_ (N_*H_)    // 32768

typedef unsigned short u16;
typedef unsigned char  u8;
typedef __bf16 v8bf __attribute__((ext_vector_type(8)));
typedef float  v4f  __attribute__((ext_vector_type(4)));
typedef float  v2f  __attribute__((ext_vector_type(2)));
typedef unsigned short v8u __attribute__((ext_vector_type(8)));

// Workspace layout (bytes):
//   0        : wbf  bf16, 4 matrices, each in MFMA-fragment order:
//              [j16 (0..31)][kk (0..15)][lane (0..63)][e (0..7)]
//   2 MB     : statsf, 6144 f32:
//     [0:512] xsum [512:1024] xsumsq [1024:1536] scale [1536:2048] shift
//     [2048:3072] esum(padded1024) [3072:4096] esumsq [4096:5120] s2p [5120:6144] sh2p
//   WS_Q : energy bf16 [nh][32][32] (67 MB)
//   WS_K : (unused)
//   WS_V : Vt fp8 [n][h][64][32]  (67 MB)
#define WS_STATS 2097152
#define WS_Q (WS_STATS + 32768)
#define WS_K (WS_Q + 67108864)
#define WS_V (WS_K + 67108864)

#define SCALE_QK 16.0f
#define SCALE_V  16.0f

__device__ __forceinline__ u16 f2bf(float f) {
  union { float f; unsigned u; } v; v.f = f;
  unsigned r = v.u + 0x7FFFu + ((v.u >> 16) & 1u);
  return (u16)(r >> 16);
}
__device__ __forceinline__ float bf2f(u16 v) {
  union { unsigned u; float f; } w; w.u = ((unsigned)v) << 16; return w.f;
}
__device__ __forceinline__ unsigned enc4(float a, float b, float c, float d) {
  int w = __builtin_amdgcn_cvt_pk_fp8_f32(a, b, 0, false);
  w = __builtin_amdgcn_cvt_pk_fp8_f32(c, d, w, true);
  return (unsigned)w;
}
__device__ __forceinline__ v8bf dec8(uint2 u) {
  v2f p0 = __builtin_amdgcn_cvt_pk_f32_fp8((int)u.x, false);
  v2f p1 = __builtin_amdgcn_cvt_pk_f32_fp8((int)u.x, true);
  v2f p2 = __builtin_amdgcn_cvt_pk_f32_fp8((int)u.y, false);
  v2f p3 = __builtin_amdgcn_cvt_pk_f32_fp8((int)u.y, true);
  v8bf r;
  r[0]=(__bf16)p0[0]; r[1]=(__bf16)p0[1]; r[2]=(__bf16)p1[0]; r[3]=(__bf16)p1[1];
  r[4]=(__bf16)p2[0]; r[5]=(__bf16)p2[1]; r[6]=(__bf16)p3[0]; r[7]=(__bf16)p3[1];
  return r;
}

// ---------------- K0: weights fp32 -> bf16 in MFMA fragment order; zero stat accumulators
__global__ void k_init(const float* wq, const float* wk, const float* wv, const float* wo,
                       u16* wbf, float* statsf) {
  int gid = blockIdx.x * 256 + threadIdx.x;   // 4096*256 = 1048576 = 4*262144
  if (gid < 6144) statsf[gid] = 0.0f;
  int m = gid >> 18, o = gid & 262143;
  int e    = o & 7;
  int lane = (o >> 3) & 63;
  int kk   = (o >> 9) & 15;
  int j16  = o >> 13;
  int j = j16 * 16 + (lane & 15);
  int k = kk * 32 + (lane >> 4) * 8 + e;
  const float* src = (m == 0) ? wq : (m == 1) ? wk : (m == 2) ? wv : wo;
  wbf[(size_t)m * 262144 + o] = f2bf(src[j * 512 + k]);
}

// ---------------- K1: per-channel sum/sumsq of x (float4 loads)
__global__ void __launch_bounds__(512) k_xstats(const float* __restrict__ x, float* statsf) {
  int t = threadIdx.x;
  int c4 = (t & 127) * 4;
  int r0 = blockIdx.x * 512 + (t >> 7) * 128;
  float4 s = {0,0,0,0}, sq = {0,0,0,0};
  const float* p = x + (size_t)r0 * C_ + c4;
  for (int i = 0; i < 128; ++i) {
    float4 v = *(const float4*)(p + (size_t)i * C_);
    s.x += v.x; s.y += v.y; s.z += v.z; s.w += v.w;
    sq.x += v.x*v.x; sq.y += v.y*v.y; sq.z += v.z*v.z; sq.w += v.w*v.w;
  }
  atomicAdd(&statsf[c4+0], s.x); atomicAdd(&statsf[c4+1], s.y);
  atomicAdd(&statsf[c4+2], s.z); atomicAdd(&statsf[c4+3], s.w);
  atomicAdd(&statsf[512+c4+0], sq.x); atomicAdd(&statsf[512+c4+1], sq.y);
  atomicAdd(&statsf[512+c4+2], sq.z); atomicAdd(&statsf[512+c4+3], sq.w);
}

__global__ void k_finalize_ch(const float* gamma, const float* beta, float* statsf) {
  int c = threadIdx.x;
  float mu  = statsf[c] * (1.0f / (float)M_);
  float var = statsf[512 + c] * (1.0f / (float)M_) - mu * mu;
  float sc  = rsqrtf(var + 1e-5f) * gamma[c];
  statsf[1024 + c] = sc;
  statsf[1536 + c] = beta[c] - mu * sc;
}

// 64x64-per-wave GEMM over the staged A fragments (s_a) and fragment-order B.
__device__ __forceinline__ void gemm64(const u16* sa, const u16* B0, v4f (&acc)[4][4], int lane) {
  #pragma unroll
  for (int m = 0; m < 4; ++m)
    #pragma unroll
    for (int c = 0; c < 4; ++c) acc[m][c] = (v4f){0,0,0,0};
  #pragma unroll 2
  for (int kk = 0; kk < 16; ++kk) {
    v8bf a[4], b[4];
    #pragma unroll
    for (int m = 0; m < 4; ++m)
      a[m] = *(const v8bf*)(sa + ((((kk*4 + m) << 6) | (lane ^ (kk & 7))) << 3));
    #pragma unroll
    for (int c = 0; c < 4; ++c)
      b[c] = *(const v8bf*)(B0 + (size_t)c * 8192 + kk * 512);
    #pragma unroll
    for (int m = 0; m < 4; ++m)
      #pragma unroll
      for (int c = 0; c < 4; ++c)
        acc[m][c] = __builtin_amdgcn_mfma_f32_16x16x32_bf16(a[m], b[c], acc[m][c], 0, 0, 0);
  }
}

// ---------------- K2: normalize -> QKV GEMMs -> in-kernel energy = Q K^T
// Block = 2 batch items (64 padded rows), 512 thr, LDS 68 KB -> 2 blocks/CU.
// Order: V (store vt) -> Q (keep fp8 in regs) -> K (keep fp8 in regs) ->
// sync -> reuse s_a as per-wave 8KB scratch -> energy -> write eg bf16.
// Q/K never touch global memory.
__global__ void __launch_bounds__(512, 4)
k_qkv(const float* __restrict__ x, const u16* __restrict__ wbf,
      const float* __restrict__ statsf, u8* __restrict__ eg8, u8* __restrict__ vt) {
  __shared__ float s_scale[C_], s_shift[C_];
  __shared__ u16 s_a[16*4*64*8];   // 64 KB; fragment order; reused as QK scratch later
  int t = threadIdx.x, nblk = blockIdx.x;
  int wave = t >> 6, lane = t & 63, l15 = lane & 15, quad = lane >> 4;
  s_scale[t] = statsf[1024+t]; s_shift[t] = statsf[1536+t];
  __syncthreads();

  // stage normalized A in fragment order (row 31 of each n zeroed): 64 rows
  const float* xb = x + (size_t)nblk * 2 * S_ * C_;
  for (int it = 0; it < 8; ++it) {
    int idx = t + it * 512;
    int row = idx >> 6, c8 = (idx & 63) << 3;
    int nl = row >> 5, s = row & 31;
    int kk = c8 >> 5, q4 = (c8 >> 3) & 3, mt = row >> 4, r15 = row & 15;
    u16* dst = s_a + ((((kk*4 + mt) << 6) | ((q4*16 + r15) ^ (kk & 7))) << 3);
    v8u o;
    if (s == 31) { o = (v8u){0,0,0,0,0,0,0,0}; }
    else {
      const float* g = xb + (size_t)(nl * 31 + s) * C_ + c8;
      float4 a = *(const float4*)g, b = *(const float4*)(g + 4);
      o[0]=f2bf(a.x*s_scale[c8+0]+s_shift[c8+0]); o[1]=f2bf(a.y*s_scale[c8+1]+s_shift[c8+1]);
      o[2]=f2bf(a.z*s_scale[c8+2]+s_shift[c8+2]); o[3]=f2bf(a.w*s_scale[c8+3]+s_shift[c8+3]);
      o[4]=f2bf(b.x*s_scale[c8+4]+s_shift[c8+4]); o[5]=f2bf(b.y*s_scale[c8+5]+s_shift[c8+5]);
      o[6]=f2bf(b.z*s_scale[c8+6]+s_shift[c8+6]); o[7]=f2bf(b.w*s_scale[c8+7]+s_shift[c8+7]);
    }
    *(v8u*)dst = o;
  }
  __syncthreads();

  v4f acc[4][4];

  // ---- V GEMM (matrix 2) -> vt fp8 [n][h=wave][64d][32s]
  gemm64(s_a, wbf + (size_t)2 * 262144 + (size_t)wave * 32768 + (size_t)lane * 8, acc, lane);
  #pragma unroll
  for (int m = 0; m < 4; ++m) {
    int rbase = m*16 + quad*4;
    int nl = rbase >> 5, s0 = rbase & 31;
    size_t nbase = (size_t)(nblk*2 + nl) * 8;
    #pragma unroll
    for (int c = 0; c < 4; ++c) {
      int d = c*16 + l15;
      unsigned w = enc4(acc[m][c][0]*SCALE_V, acc[m][c][1]*SCALE_V,
                        acc[m][c][2]*SCALE_V, acc[m][c][3]*SCALE_V);
      *(unsigned*)(vt + ((nbase + wave) * 2048) + d*32 + s0) = w;
    }
  }

  // ---- Q GEMM (matrix 0) -> fp8 packed in regs (head = wave, both n)
  unsigned qpack[16];
  gemm64(s_a, wbf + (size_t)0 * 262144 + (size_t)wave * 32768 + (size_t)lane * 8, acc, lane);
  #pragma unroll
  for (int m = 0; m < 4; ++m)
    #pragma unroll
    for (int c = 0; c < 4; ++c)
      qpack[m*4+c] = enc4(acc[m][c][0]*SCALE_QK, acc[m][c][1]*SCALE_QK,
                          acc[m][c][2]*SCALE_QK, acc[m][c][3]*SCALE_QK);

  // ---- K GEMM (matrix 1) -> fp8 packed in regs
  unsigned kpack[16];
  gemm64(s_a, wbf + (size_t)1 * 262144 + (size_t)wave * 32768 + (size_t)lane * 8, acc, lane);
  #pragma unroll
  for (int m = 0; m < 4; ++m)
    #pragma unroll
    for (int c = 0; c < 4; ++c)
      kpack[m*4+c] = enc4(acc[m][c][0]*SCALE_QK, acc[m][c][1]*SCALE_QK,
                          acc[m][c][2]*SCALE_QK, acc[m][c][3]*SCALE_QK);

  __syncthreads();   // all waves done reading s_a fragments -> safe to reuse as scratch

  // per-wave scratch: Q tile [r(64)][d(64)] fp8 at +0, K tile at +4096.
  // XOR-swizzle d ^= (r&7)<<3 keeps writes ~2-way conflict (free) and reads vectorizable.
  u8* scr = (u8*)s_a + wave * 8192;
  #pragma unroll
  for (int m = 0; m < 4; ++m)
    #pragma unroll
    for (int c = 0; c < 4; ++c) {
      int d = c*16 + l15;
      #pragma unroll
      for (int reg = 0; reg < 4; ++reg) {
        int r = m*16 + quad*4 + reg;
        int dd = d ^ ((r & 7) << 3);
        scr[r*64 + dd]        = (u8)(qpack[m*4+c] >> (reg*8));
        scr[4096 + r*64 + dd] = (u8)(kpack[m*4+c] >> (reg*8));
      }
    }

  // ---- energy = Q K^T per (n, h=wave), bf16 [32][32] -> eg
  const float inv = 1.0f / (SCALE_QK * SCALE_QK);
  #pragma unroll 1
  for (int n = 0; n < 2; ++n) {
    v8bf A[2][2], B[2][2];
    #pragma unroll
    for (int mt = 0; mt < 2; ++mt)
      #pragma unroll
      for (int kk = 0; kk < 2; ++kk) {
        int r = n*32 + mt*16 + l15;
        int dA = (kk*32 + quad*8) ^ ((r & 7) << 3);
        A[mt][kk] = dec8(*(const uint2*)(scr + r*64 + dA));
        B[mt][kk] = dec8(*(const uint2*)(scr + 4096 + r*64 + dA));
      }
    u16* ep = (u16*)(eg8 + (((size_t)(nblk*2 + n) * 8 + wave) * 2048));
    #pragma unroll
    for (int qt = 0; qt < 2; ++qt)
      #pragma unroll
      for (int kt = 0; kt < 2; ++kt) {
        v4f a2 = {0,0,0,0};
        a2 = __builtin_amdgcn_mfma_f32_16x16x32_bf16(A[qt][0], B[kt][0], a2, 0, 0, 0);
        a2 = __builtin_amdgcn_mfma_f32_16x16x32_bf16(A[qt][1], B[kt][1], a2, 0, 0, 0);
        int k = kt*16 + l15;
        #pragma unroll
        for (int reg = 0; reg < 4; ++reg) {
          int q = qt*16 + quad*4 + reg;
          ep[q*32 + k] = f2bf(a2[reg] * inv);
        }
      }
  }
}

// ---------------- K4: energy per-padded-channel sum/sumsq over (n,h)
__global__ void __launch_bounds__(256) k_estats(const u16* __restrict__ eg, float* statsf) {
  int t = threadIdx.x;
  int r0 = blockIdx.x * 128;
  float s[4] = {0,0,0,0}, sq[4] = {0,0,0,0};
  for (int i = 0; i < 128; ++i) {
    uint2 u = *(const uint2*)(eg + (size_t)(r0 + i) * 1024 + t * 4);
    float v0 = bf2f((u16)(u.x & 0xffff)), v1 = bf2f((u16)(u.x >> 16));
    float v2 = bf2f((u16)(u.y & 0xffff)), v3 = bf2f((u16)(u.y >> 16));
    s[0]+=v0; s[1]+=v1; s[2]+=v2; s[3]+=v3;
    sq[0]+=v0*v0; sq[1]+=v1*v1; sq[2]+=v2*v2; sq[3]+=v3*v3;
  }
  #pragma unroll
  for (int j = 0; j < 4; ++j) {
    atomicAdd(&statsf[2048 + t*4 + j], s[j]);
    atomicAdd(&statsf[3072 + t*4 + j], sq[j]);
  }
}

__global__ void k_finalize_e(const float* pg, const float* pb, float* statsf) {
  int c = threadIdx.x;       // 1024
  int q = c >> 5, k = c & 31;
  const float invC = 0.04419417382415922f;   // 1/sqrt(512)
  float s2 = 0.f, sh2 = 0.f;
  if (q < 31 && k < 31) {
    int ss = q*31 + k;
    float mu  = statsf[2048 + c] * (1.0f / (float)NH_);
    float var = statsf[3072 + c] * (1.0f / (float)NH_) - mu * mu;
    float sc  = rsqrtf(var + 1e-5f) * pg[ss];
    s2  = sc * invC;
    sh2 = (pb[ss] - mu * sc) * invC;
  }
  statsf[4096 + c] = s2;
  statsf[5120 + c] = sh2;
}

// ---------------- K5: softmax + A*V -> LDS A, then O-proj GEMM + bias + residual
// Block = 2 batch items, LDS 80 KB (64 KB s_a + 16 KB s_attn) -> 2 blocks/CU.
__global__ void __launch_bounds__(512, 4)
k_oproj(const float* __restrict__ x, const u16* __restrict__ wbf,
        const float* __restrict__ statsf, const u16* __restrict__ eg,
        const u8* __restrict__ vt, const float* __restrict__ bo, float* __restrict__ out) {
  __shared__ u16 s_a[16*4*64*8];        // 64 KB, fragment order
  __shared__ u16 s_attn[8][1024];       // per-wave [32 q][32 k] bf16, 16 KB
  int t = threadIdx.x, nblk = blockIdx.x;
  int wave = t >> 6, lane = t & 63, l15 = lane & 15, quad = lane >> 4;

  // phase 1: 16 tasks = 2n x 8h; wave handles 2
  int q = lane & 31, half = lane >> 5;
  #pragma unroll 1
  for (int tk = 0; tk < 2; ++tk) {
    int task = wave * 2 + tk;
    int nl = task >> 3, h = task & 7;
    size_t nh = (size_t)(nblk*2 + nl) * 8 + h;
    const u16* ep = eg + nh * 1024;
    int cb = q*32 + half*16;
    v8u e0 = *(const v8u*)(ep + cb);
    v8u e1 = *(const v8u*)(ep + cb + 8);
    const float* s2g  = statsf + 4096 + cb;
    const float* sh2g = statsf + 5120 + cb;
    float lg[16];
    #pragma unroll
    for (int j = 0; j < 8; ++j) lg[j]   = bf2f(e0[j]) * s2g[j]   + sh2g[j];
    #pragma unroll
    for (int j = 0; j < 8; ++j) lg[8+j] = bf2f(e1[j]) * s2g[8+j] + sh2g[8+j];
    if (half) lg[15] = -1e30f;            // k=31 pad excluded
    float mx = lg[0];
    #pragma unroll
    for (int j = 1; j < 16; ++j) mx = fmaxf(mx, lg[j]);
    mx = fmaxf(mx, __shfl_xor(mx, 32));
    float sum = 0.f;
    #pragma unroll
    for (int j = 0; j < 16; ++j) { lg[j] = __expf(lg[j] - mx); sum += lg[j]; }
    sum += __shfl_xor(sum, 32);
    float r = (q == 31) ? 0.f : (1.0f / sum);
    v8u o0, o1;
    #pragma unroll
    for (int j = 0; j < 8; ++j) { o0[j] = f2bf(lg[j] * r); o1[j] = f2bf(lg[8+j] * r); }
    *(v8u*)(&s_attn[wave][cb]) = o0;
    *(v8u*)(&s_attn[wave][cb + 8]) = o1;
    // A*V for this (n,h)
    v8bf a0 = *(const v8bf*)(&s_attn[wave][(l15)*32 + quad*8]);
    v8bf a1 = *(const v8bf*)(&s_attn[wave][(16 + l15)*32 + quad*8]);
    const float invV = 1.0f / SCALE_V;
    #pragma unroll
    for (int ct = 0; ct < 4; ++ct) {
      uint2 u = *(const uint2*)(vt + nh*2048 + (ct*16 + l15)*32 + quad*8);
      v8bf b = dec8(u);
      v4f c0 = {0,0,0,0}, c1 = {0,0,0,0};
      c0 = __builtin_amdgcn_mfma_f32_16x16x32_bf16(a0, b, c0, 0, 0, 0);
      c1 = __builtin_amdgcn_mfma_f32_16x16x32_bf16(a1, b, c1, 0, 0, 0);
      int ch = h*64 + ct*16 + l15;
      int kkA = ch >> 5, qA = (ch >> 3) & 3, pA = ch & 7;
      #pragma unroll
      for (int reg = 0; reg < 4; ++reg) {
        int rm = quad*4 + reg;
        s_a[((((kkA*4 + nl*2 + 0) << 6) | (qA*16 + rm)) << 3) + pA] = f2bf(c0[reg] * invV);
        s_a[((((kkA*4 + nl*2 + 1) << 6) | (qA*16 + rm)) << 3) + pA] = f2bf(c1[reg] * invV);
      }
    }
  }
  __syncthreads();

  // phase 2: O-proj GEMM (matrix 3 of wbf, fragment order), bias + residual, fp32 out
  {
    const u16* B0 = wbf + (size_t)3 * 262144 + (size_t)wave * 32768 + (size_t)lane * 8;
    v4f acc[4][4];
    #pragma unroll
    for (int m = 0; m < 4; ++m)
      #pragma unroll
      for (int c = 0; c < 4; ++c) acc[m][c] = (v4f){0,0,0,0};
    #pragma unroll 2
    for (int kk = 0; kk < 16; ++kk) {
      v8bf a[4], b[4];
      #pragma unroll
      for (int m = 0; m < 4; ++m)
        a[m] = *(const v8bf*)(s_a + ((((kk*4 + m) << 6) | lane) << 3));
      #pragma unroll
      for (int c = 0; c < 4; ++c)
        b[c] = *(const v8bf*)(B0 + (size_t)c * 8192 + kk * 512);
      #pragma unroll
      for (int m = 0; m < 4; ++m)
        #pragma unroll
        for (int c = 0; c < 4; ++c)
          acc[m][c] = __builtin_amdgcn_mfma_f32_16x16x32_bf16(a[m], b[c], acc[m][c], 0, 0, 0);
    }
    #pragma unroll
    for (int m = 0; m < 4; ++m) {
      int rbase = m*16 + quad*4;
      int nl = rbase >> 5, s0 = rbase & 31;
      #pragma unroll
      for (int c = 0; c < 4; ++c) {
        int j = wave*64 + c*16 + l15;
        float bj = bo[j];
        #pragma unroll
        for (int reg = 0; reg < 4; ++reg) {
          int s = s0 + reg;
          if (s < 31) {
            size_t off = (size_t)((nblk*2 + nl) * 31 + s) * C_ + j;
            out[off] = acc[m][c][reg] + bj + x[off];
          }
        }
      }
    }
  }
}

extern "C" void kernel_launch(void* const* d_in, const int* in_sizes, int n_in,
                              void* d_out, int out_size, void* d_ws, size_t ws_size,
                              hipStream_t stream) {
  const float* x     = (const float*)d_in[0];
  const float* gamma = (const float*)d_in[1];
  const float* beta  = (const float*)d_in[2];
  const float* wq    = (const float*)d_in[3];
  const float* wk    = (const float*)d_in[4];
  const float* wv    = (const float*)d_in[5];
  const float* wo    = (const float*)d_in[6];
  const float* bo    = (const float*)d_in[7];
  const float* pg    = (const float*)d_in[8];
  const float* pb    = (const float*)d_in[9];

  char* ws = (char*)d_ws;
  u16*   wbf    = (u16*)ws;
  float* statsf = (float*)(ws + WS_STATS);
  u8*    eg8    = (u8*)(ws + WS_Q);
  u8*    vtp    = (u8*)(ws + WS_V);
  float* outp   = (float*)d_out;

  k_init<<<4096, 256, 0, stream>>>(wq, wk, wv, wo, wbf, statsf);
  k_xstats<<<248, 512, 0, stream>>>(x, statsf);
  k_finalize_ch<<<1, 512, 0, stream>>>(gamma, beta, statsf);
  k_qkv<<<2048, 512, 0, stream>>>(x, wbf, statsf, eg8, vtp);
  k_estats<<<256, 256, 0, stream>>>((const u16*)eg8, statsf);
  k_finalize_e<<<1, 1024, 0, stream>>>(pg, pb, statsf);
  k_oproj<<<2048, 512, 0, stream>>>(x, wbf, statsf, (const u16*)eg8, vtp, bo, outp);
}